// Round 9
// baseline (46.075 us; speedup 1.0000x reference)
//
#include <hip/hip_runtime.h>
#include <hip/hip_bf16.h>

// 3x3 median pool, stride 1, zero-pad 1, fp32 in/out.
// Input: (8, 64, 256, 256) => 512 planes of 256x256.
//
// 4-wide x 4-tall tiles (16 outputs/thread), 64 lanes = one full image row:
//   - every wave load/store instruction is 64 lanes x 16B = 1KB fully
//     contiguous (full cachelines -> NT stores can't cause partial-line RMW),
//   - halo columns via neighbor-lane shfl; lane 0/63 boundary == image edge
//     (zero pad), so no misaligned or scalar loads at all,
//   - NON-TEMPORAL full-line stores: output bypasses L3 allocation, so the
//     134MB input stays resident in the 256MB Infinity Cache across graph
//     replays (FETCH_SIZE is the signature: 69MB -> ~0 if this works),
//   - exact median-of-9 via column-sort factorization (v_min3/v_med3/v_max3).

typedef float vf4 __attribute__((ext_vector_type(4)));

__device__ __forceinline__ float min3f(float a, float b, float c) {
    return fminf(fminf(a, b), c);
}
__device__ __forceinline__ float max3f(float a, float b, float c) {
    return fmaxf(fmaxf(a, b), c);
}
__device__ __forceinline__ float med3f(float a, float b, float c) {
    return __builtin_amdgcn_fmed3f(a, b, c);
}

__global__ __launch_bounds__(256)
void median3x3_kernel(const float* __restrict__ x, float* __restrict__ y, int total) {
    int idx = blockIdx.x * blockDim.x + threadIdx.x;
    if (idx >= total) return;

    // Decomposition: 64 col-groups (4 wide) x 64 row-strips (4 tall) x 512 planes.
    // All 64 lanes of a wave share (hs, p): one wave = 4 full output rows.
    const int w4 = idx & 63;
    const int hs = (idx >> 6) & 63;
    const int p  = idx >> 12;

    const float* plane = x + ((size_t)p << 16);   // 256*256 floats per plane
    const int c0 = w4 << 2;                        // first output column
    const int h0 = hs << 2;                        // first output row

    // Load 6 input rows (h0-1 .. h0+4): one aligned float4 each, predicated on
    // row validity (no branch around the shfls below).
    float r[6][6];
#pragma unroll
    for (int t = 0; t < 6; ++t) {
        const int hh = h0 + t - 1;
        vf4 a = (vf4)0.f;
        if (hh >= 0 && hh <= 255) {
            a = *reinterpret_cast<const vf4*>(plane + (hh << 8) + c0);
        }
        r[t][1] = a.x; r[t][2] = a.y; r[t][3] = a.z; r[t][4] = a.w;
        // Halo from neighbor lanes; lane 0 / lane 63 are the image edges.
        const float left  = __shfl_up(a.w, 1);    // lane-1's col c0-1
        const float right = __shfl_down(a.x, 1);  // lane+1's col c0+4
        r[t][0] = (w4 == 0)  ? 0.f : left;
        r[t][5] = (w4 == 63) ? 0.f : right;
    }

    float* outbase = y + ((size_t)p << 16) + ((size_t)h0 << 8) + c0;

#pragma unroll
    for (int orow = 0; orow < 4; ++orow) {
        // Column-wise vertical sort over rows orow..orow+2.
        float lo[6], mi[6], hi[6];
#pragma unroll
        for (int j = 0; j < 6; ++j) {
            const float a = r[orow][j], b = r[orow + 1][j], c = r[orow + 2][j];
            lo[j] = min3f(a, b, c);
            mi[j] = med3f(a, b, c);
            hi[j] = max3f(a, b, c);
        }
        float res[4];
#pragma unroll
        for (int k = 0; k < 4; ++k) {
            const float A = max3f(lo[k], lo[k + 1], lo[k + 2]);
            const float B = med3f(mi[k], mi[k + 1], mi[k + 2]);
            const float C = min3f(hi[k], hi[k + 1], hi[k + 2]);
            res[k] = med3f(A, B, C);
        }
        vf4 o = {res[0], res[1], res[2], res[3]};
        __builtin_nontemporal_store(o, reinterpret_cast<vf4*>(outbase + (orow << 8)));
    }
}

extern "C" void kernel_launch(void* const* d_in, const int* in_sizes, int n_in,
                              void* d_out, int out_size, void* d_ws, size_t ws_size,
                              hipStream_t stream) {
    const float* x = (const float*)d_in[0];
    float* y = (float*)d_out;
    const int total = out_size / 16;            // 2,097,152 threads (4x4 tiles)
    const int threads = 256;
    const int blocks = (total + threads - 1) / threads;
    median3x3_kernel<<<blocks, threads, 0, stream>>>(x, y, total);
}